// Round 6
// baseline (2981.826 us; speedup 1.0000x reference)
//
#include <hip/hip_runtime.h>

#define N_ROWS 10000
#define DIM    768
#define NCLS   1000
#define KNB    10
#define NITER  20
#define EPSV   1e-8f
#define JSPLIT 16
#define NRT    79      // row tiles of 128
#define NJT    79      // col tiles of 128
#define NCT    8       // classifier col tiles of 128
#define MAXE   2048
#define STR    40      // legacy padded stride (gemm2 only)

typedef __attribute__((ext_vector_type(8))) short s8b;             // MFMA bf16 frag
typedef __attribute__((ext_vector_type(4))) float f4;              // MFMA acc
typedef __attribute__((ext_vector_type(8))) unsigned short us8;
typedef __attribute__((ext_vector_type(4))) unsigned short us4;

__device__ __forceinline__ unsigned short f2bf(float x) {
    unsigned u = __float_as_uint(x);
    unsigned r = u + 0x7FFFu + ((u >> 16) & 1u);   // RN-even
    return (unsigned short)(r >> 16);
}
__device__ __forceinline__ float bf2f(unsigned short b) {
    return __uint_as_float(((unsigned)b) << 16);
}

// ---------------- row normalize -> bf16 hi/lo split + norm save ----------------
__global__ __launch_bounds__(192) void rownorm2_k(const float* __restrict__ feat,
                                                  unsigned short* __restrict__ nfh,
                                                  unsigned short* __restrict__ nfl,
                                                  float* __restrict__ rnorm) {
    int row = blockIdx.x;
    int t = threadIdx.x;
    const float4* src = (const float4*)(feat + (size_t)row * DIM);
    float4 v = src[t];
    float ss = v.x*v.x + v.y*v.y + v.z*v.z + v.w*v.w;
#pragma unroll
    for (int m = 1; m < 64; m <<= 1) ss += __shfl_xor(ss, m, 64);
    __shared__ float red[3];
    if ((t & 63) == 0) red[t >> 6] = ss;
    __syncthreads();
    float nrm = sqrtf(red[0] + red[1] + red[2]) + EPSV;
    float inv = 1.0f / nrm;
    if (t == 0) rnorm[row] = nrm;
    float xs[4] = {v.x*inv, v.y*inv, v.z*inv, v.w*inv};
    us4 h, l;
#pragma unroll
    for (int j = 0; j < 4; ++j) {
        unsigned short hb = f2bf(xs[j]);
        h[j] = hb;
        l[j] = f2bf(xs[j] - bf2f(hb));
    }
    *(us4*)(nfh + (size_t)row * DIM + t*4) = h;
    *(us4*)(nfl + (size_t)row * DIM + t*4) = l;
}

// ---------------- generic fp32 -> bf16 hi/lo split (for cw) ----------------
__global__ void split_k(const float* __restrict__ src,
                        unsigned short* __restrict__ h,
                        unsigned short* __restrict__ l, int n4) {
    int i = blockIdx.x * blockDim.x + threadIdx.x;
    if (i >= n4) return;
    float4 v = ((const float4*)src)[i];
    float xs[4] = {v.x, v.y, v.z, v.w};
    us4 hh, ll;
#pragma unroll
    for (int j = 0; j < 4; ++j) {
        unsigned short hb = f2bf(xs[j]);
        hh[j] = hb;
        ll[j] = f2bf(xs[j] - bf2f(hb));
    }
    ((us4*)h)[i] = hh; ((us4*)l)[i] = ll;
}

// ---------------- fused sims: A-frags direct from global, B via swizzled LDS ----------------
// Swizzle: halfword offset(row, slot) = row*32 + 8*(slot ^ ((row>>1)&3)); slot = 16B k-quarter.
// Verified uniform 8-lanes/bank-quad for BOTH the frag-read pattern (16 rows x 4 g) and the
// staging-write pattern (2 us8 per plane per thread) -> conflict-free.
__global__ __launch_bounds__(256, 2) void simtopk_k(const unsigned short* __restrict__ nfh,
                                                    const unsigned short* __restrict__ nfl,
                                                    float* __restrict__ pv,
                                                    int* __restrict__ pi_) {
    __shared__ __align__(16) unsigned short BS[2][2][128 * 32];   // 32 KiB (dbuf x {hi,lo})

    int tid = threadIdx.x;
    int l = tid & 63, w = tid >> 6;           // wave w: rows w*32 .. +31
    int g = l >> 4, c = l & 15;

    int id = blockIdx.x;
    int pos = id >> 3, x8 = id & 7;           // XCD-grouped swizzle
    int bi = pos % NRT;
    int js = x8 + 8 * (pos / NRT);
    int m0 = bi * 128;

    float lv[2][10]; int li[2][10];
#pragma unroll
    for (int rf = 0; rf < 2; ++rf)
#pragma unroll
        for (int s = 0; s < 10; ++s) { lv[rf][s] = -1e30f; li[rf][s] = 0x7fffffff; }

    // B staging: thread stages row srow, k-half skh (16 halfwords = slots 2skh, 2skh+1)
    int srow = tid >> 1, skh = tid & 1;
    int sw = (srow >> 1) & 3;
    int wb0 = srow * 32 + 8 * ((2 * skh)     ^ sw);
    int wb1 = srow * 32 + 8 * ((2 * skh + 1) ^ sw);

    // A direct rows (held in regs, k-frag loaded per chunk)
    int ar0 = m0 + w * 32 + c;
    int ar1 = ar0 + 16;
    bool av0 = ar0 < N_ROWS, av1 = ar1 < N_ROWS;
    const size_t a0 = (size_t)ar0 * DIM + g * 8;
    const size_t a1 = (size_t)ar1 * DIM + g * 8;

    // B frag read base: row = cf*16 + c, slot g -> swizzled
    int rbo = c * 32 + 8 * (g ^ ((c >> 1) & 3));   // + cf*512

    // prologue: B regs (jt=js, ch=0) and A frags (ch=0)
    us8 rbh0, rbh1, rbl0, rbl1;
    {
        int bgr = js * 128 + srow;
        bool bv = bgr < N_ROWS;
        size_t bb = (size_t)bgr * DIM + skh * 16;
        rbh0 = bv ? *(const us8*)(nfh + bb)     : (us8)0;
        rbh1 = bv ? *(const us8*)(nfh + bb + 8) : (us8)0;
        rbl0 = bv ? *(const us8*)(nfl + bb)     : (us8)0;
        rbl1 = bv ? *(const us8*)(nfl + bb + 8) : (us8)0;
    }
    us8 cah0 = av0 ? *(const us8*)(nfh + a0) : (us8)0;
    us8 cah1 = av1 ? *(const us8*)(nfh + a1) : (us8)0;
    us8 cal0 = av0 ? *(const us8*)(nfl + a0) : (us8)0;
    us8 cal1 = av1 ? *(const us8*)(nfl + a1) : (us8)0;

    for (int jt = js; jt < NJT; jt += JSPLIT) {
        f4 acc[2][8];
#pragma unroll
        for (int rf = 0; rf < 2; ++rf)
#pragma unroll
            for (int cf = 0; cf < 8; ++cf) acc[rf][cf] = (f4)0.0f;

        for (int ch = 0; ch < DIM / 32; ++ch) {
            int p = ch & 1;
            // staged B regs -> LDS buf p (readers of buf p finished: barrier ch-1 + lgkm drain)
            *(us8*)(&BS[p][0][wb0]) = rbh0;  *(us8*)(&BS[p][0][wb1]) = rbh1;
            *(us8*)(&BS[p][1][wb0]) = rbl0;  *(us8*)(&BS[p][1][wb1]) = rbl1;
            __syncthreads();

            int nch = ch + 1, njt = jt;
            if (nch == DIM / 32) { nch = 0; njt = jt + JSPLIT; }
            us8 nah0 = cah0, nah1 = cah1, nal0 = cal0, nal1 = cal1;
            if (njt < NJT) {
                // next B tile chunk
                int nbgr = njt * 128 + srow;
                bool nbv = nbgr < N_ROWS;
                size_t nbb = (size_t)nbgr * DIM + skh * 16 + (size_t)nch * 32;
                rbh0 = nbv ? *(const us8*)(nfh + nbb)     : (us8)0;
                rbh1 = nbv ? *(const us8*)(nfh + nbb + 8) : (us8)0;
                rbl0 = nbv ? *(const us8*)(nfl + nbb)     : (us8)0;
                rbl1 = nbv ? *(const us8*)(nfl + nbb + 8) : (us8)0;
                // next A frags (rows fixed, k advances)
                size_t ak = (size_t)nch * 32;
                nah0 = av0 ? *(const us8*)(nfh + a0 + ak) : (us8)0;
                nah1 = av1 ? *(const us8*)(nfh + a1 + ak) : (us8)0;
                nal0 = av0 ? *(const us8*)(nfl + a0 + ak) : (us8)0;
                nal1 = av1 ? *(const us8*)(nfl + a1 + ak) : (us8)0;
            }
#pragma unroll
            for (int cf = 0; cf < 8; ++cf) {
                s8b bh = *(const s8b*)(&BS[p][0][rbo + cf * 512]);
                s8b bl = *(const s8b*)(&BS[p][1][rbo + cf * 512]);
                acc[0][cf] = __builtin_amdgcn_mfma_f32_16x16x32_bf16(bh, (s8b)cah0, acc[0][cf], 0, 0, 0);
                acc[1][cf] = __builtin_amdgcn_mfma_f32_16x16x32_bf16(bh, (s8b)cah1, acc[1][cf], 0, 0, 0);
                acc[0][cf] = __builtin_amdgcn_mfma_f32_16x16x32_bf16(bl, (s8b)cah0, acc[0][cf], 0, 0, 0);
                acc[1][cf] = __builtin_amdgcn_mfma_f32_16x16x32_bf16(bl, (s8b)cah1, acc[1][cf], 0, 0, 0);
                acc[0][cf] = __builtin_amdgcn_mfma_f32_16x16x32_bf16(bh, (s8b)cal0, acc[0][cf], 0, 0, 0);
                acc[1][cf] = __builtin_amdgcn_mfma_f32_16x16x32_bf16(bh, (s8b)cal1, acc[1][cf], 0, 0, 0);
            }
            cah0 = nah0; cah1 = nah1; cal0 = nal0; cal1 = nal1;
        }

        // in-register top-10 update (all static indices)
#pragma unroll
        for (int rf = 0; rf < 2; ++rf) {
            int row = m0 + w * 32 + rf * 16 + c;
#pragma unroll
            for (int cf = 0; cf < 8; ++cf) {
                f4 a = acc[rf][cf];
                int col0 = jt * 128 + cf * 16 + g * 4;
                float mx = fmaxf(fmaxf(a[0], a[1]), fmaxf(a[2], a[3]));
                if (mx > lv[rf][9]) {
#pragma unroll
                    for (int r = 0; r < 4; ++r) {
                        int col = col0 + r;
                        float val = a[r];
                        if (col < N_ROWS && col != row && val > lv[rf][9]) {
                            lv[rf][9] = val; li[rf][9] = col;
#pragma unroll
                            for (int u = 9; u > 0; --u) {
                                if (lv[rf][u] > lv[rf][u-1]) {
                                    float t2 = lv[rf][u]; lv[rf][u] = lv[rf][u-1]; lv[rf][u-1] = t2;
                                    int   t3 = li[rf][u]; li[rf][u] = li[rf][u-1]; li[rf][u-1] = t3;
                                }
                            }
                        }
                    }
                }
            }
        }
    }

    // merge across the 4 g-lanes sharing each row (butterfly xor 16,32), write partial list
#pragma unroll
    for (int rf = 0; rf < 2; ++rf) {
        int grow = m0 + w * 32 + rf * 16 + c;
#pragma unroll 1
        for (int sel = 0; sel < KNB; ++sel) {
            float cv = lv[rf][0]; int ci = li[rf][0];
            float bv = cv; int bi2 = ci;
            float ov = __shfl_xor(bv, 16, 64); int oi = __shfl_xor(bi2, 16, 64);
            if (ov > bv || (ov == bv && oi < bi2)) { bv = ov; bi2 = oi; }
            ov = __shfl_xor(bv, 32, 64); oi = __shfl_xor(bi2, 32, 64);
            if (ov > bv || (ov == bv && oi < bi2)) { bv = ov; bi2 = oi; }
            if (cv == bv && ci == bi2) {  // I won: pop my head
#pragma unroll
                for (int s = 0; s < 9; ++s) { lv[rf][s] = lv[rf][s+1]; li[rf][s] = li[rf][s+1]; }
                lv[rf][9] = -1e30f; li[rf][9] = 0x7fffffff;
            }
            if (g == 0 && grow < N_ROWS) {
                size_t o = ((size_t)js * N_ROWS + grow) * KNB + sel;
                pv[o] = bv; pi_[o] = bi2;
            }
        }
    }
}

// ---------------- classifier logits: bf16 hi/lo split MFMA, scaled by row norm ----------------
__global__ __launch_bounds__(256, 2) void gemm2_k(const unsigned short* __restrict__ nfh,
                                                  const unsigned short* __restrict__ nfl,
                                                  const unsigned short* __restrict__ cwh,
                                                  const unsigned short* __restrict__ cwl,
                                                  const float* __restrict__ rnorm,
                                                  float* __restrict__ logits) {
    __shared__ __align__(16) unsigned short S[2][4][128 * STR];
    int tid = threadIdx.x;
    int l = tid & 63, w = tid >> 6;
    int g = l >> 4, c = l & 15;
    int m0 = blockIdx.x * 128, n0 = blockIdx.y * 128;

    int srow = tid >> 1, skh = tid & 1;
    int agr = m0 + srow;
    bool aval = agr < N_ROWS;
    size_t abase = (size_t)agr * DIM + skh * 16;
    int bgr = n0 + srow;
    bool bval = bgr < NCLS;
    size_t bbase = (size_t)bgr * DIM + skh * 16;
    int lbase = srow * STR + skh * 16;

    us8 rah0, rah1, ral0, ral1, rbh0, rbh1, rbl0, rbl1;
    rah0 = aval ? *(const us8*)(nfh + abase)     : (us8)0;
    rah1 = aval ? *(const us8*)(nfh + abase + 8) : (us8)0;
    ral0 = aval ? *(const us8*)(nfl + abase)     : (us8)0;
    ral1 = aval ? *(const us8*)(nfl + abase + 8) : (us8)0;
    rbh0 = bval ? *(const us8*)(cwh + bbase)     : (us8)0;
    rbh1 = bval ? *(const us8*)(cwh + bbase + 8) : (us8)0;
    rbl0 = bval ? *(const us8*)(cwl + bbase)     : (us8)0;
    rbl1 = bval ? *(const us8*)(cwl + bbase + 8) : (us8)0;

    f4 acc[2][8];
#pragma unroll
    for (int rf = 0; rf < 2; ++rf)
#pragma unroll
        for (int cf = 0; cf < 8; ++cf) acc[rf][cf] = (f4)0.0f;

    for (int ch = 0; ch < DIM / 32; ++ch) {
        int p = ch & 1;
        *(us8*)(&S[p][0][lbase])     = rah0;  *(us8*)(&S[p][0][lbase + 8]) = rah1;
        *(us8*)(&S[p][1][lbase])     = ral0;  *(us8*)(&S[p][1][lbase + 8]) = ral1;
        *(us8*)(&S[p][2][lbase])     = rbh0;  *(us8*)(&S[p][2][lbase + 8]) = rbh1;
        *(us8*)(&S[p][3][lbase])     = rbl0;  *(us8*)(&S[p][3][lbase + 8]) = rbl1;
        __syncthreads();
        if (ch + 1 < DIM / 32) {
            size_t ao = abase + (size_t)(ch + 1) * 32;
            size_t bo = bbase + (size_t)(ch + 1) * 32;
            rah0 = aval ? *(const us8*)(nfh + ao)     : (us8)0;
            rah1 = aval ? *(const us8*)(nfh + ao + 8) : (us8)0;
            ral0 = aval ? *(const us8*)(nfl + ao)     : (us8)0;
            ral1 = aval ? *(const us8*)(nfl + ao + 8) : (us8)0;
            rbh0 = bval ? *(const us8*)(cwh + bo)     : (us8)0;
            rbh1 = bval ? *(const us8*)(cwh + bo + 8) : (us8)0;
            rbl0 = bval ? *(const us8*)(cwl + bo)     : (us8)0;
            rbl1 = bval ? *(const us8*)(cwl + bo + 8) : (us8)0;
        }
        s8b ah0 = *(const s8b*)(&S[p][0][(w*32 +  0 + c) * STR + g*8]);
        s8b ah1 = *(const s8b*)(&S[p][0][(w*32 + 16 + c) * STR + g*8]);
        s8b al0 = *(const s8b*)(&S[p][1][(w*32 +  0 + c) * STR + g*8]);
        s8b al1 = *(const s8b*)(&S[p][1][(w*32 + 16 + c) * STR + g*8]);
#pragma unroll
        for (int cf = 0; cf < 8; ++cf) {
            s8b bh = *(const s8b*)(&S[p][2][(cf*16 + c) * STR + g*8]);
            s8b bl = *(const s8b*)(&S[p][3][(cf*16 + c) * STR + g*8]);
            acc[0][cf] = __builtin_amdgcn_mfma_f32_16x16x32_bf16(bh, ah0, acc[0][cf], 0, 0, 0);
            acc[0][cf] = __builtin_amdgcn_mfma_f32_16x16x32_bf16(bl, ah0, acc[0][cf], 0, 0, 0);
            acc[0][cf] = __builtin_amdgcn_mfma_f32_16x16x32_bf16(bh, al0, acc[0][cf], 0, 0, 0);
            acc[1][cf] = __builtin_amdgcn_mfma_f32_16x16x32_bf16(bh, ah1, acc[1][cf], 0, 0, 0);
            acc[1][cf] = __builtin_amdgcn_mfma_f32_16x16x32_bf16(bl, ah1, acc[1][cf], 0, 0, 0);
            acc[1][cf] = __builtin_amdgcn_mfma_f32_16x16x32_bf16(bh, al1, acc[1][cf], 0, 0, 0);
        }
    }
#pragma unroll
    for (int rf = 0; rf < 2; ++rf) {
        int row = m0 + w*32 + rf*16 + c;
        if (row < N_ROWS) {
            float rn = rnorm[row];
#pragma unroll
            for (int cf = 0; cf < 8; ++cf) {
                f4 a = acc[rf][cf];
#pragma unroll
                for (int r = 0; r < 4; ++r) {
                    int col = n0 + cf*16 + g*4 + r;
                    if (col < NCLS) logits[(size_t)row * NCLS + col] = a[r] * rn;
                }
            }
        }
    }
}

// ---------------- row softmax (C=1000) ----------------
__global__ __launch_bounds__(256) void softmax_k(const float* __restrict__ logits,
                                                 float* __restrict__ Y) {
    int row = blockIdx.x;
    const float* src = logits + (size_t)row * NCLS;
    __shared__ float sl[NCLS];
    __shared__ float red[4];
    int t = threadIdx.x;
    float mx = -1e30f;
    for (int cc = t; cc < NCLS; cc += 256) { float x = src[cc]; sl[cc] = x; mx = fmaxf(mx, x); }
#pragma unroll
    for (int m = 1; m < 64; m <<= 1) mx = fmaxf(mx, __shfl_xor(mx, m, 64));
    if ((t & 63) == 0) red[t >> 6] = mx;
    __syncthreads();
    mx = fmaxf(fmaxf(red[0], red[1]), fmaxf(red[2], red[3]));
    float sum = 0.f;
    for (int cc = t; cc < NCLS; cc += 256) { float e = expf(sl[cc] - mx); sl[cc] = e; sum += e; }
#pragma unroll
    for (int m = 1; m < 64; m <<= 1) sum += __shfl_xor(sum, m, 64);
    __syncthreads();
    if ((t & 63) == 0) red[t >> 6] = sum;
    __syncthreads();
    float inv = 1.0f / (red[0] + red[1] + red[2] + red[3]);
    float* dst = Y + (size_t)row * NCLS;
    for (int cc = t; cc < NCLS; cc += 256) dst[cc] = sl[cc] * inv;
}

// ---------------- final merge of JSPLIT partial top-10 lists ----------------
__global__ void topmerge_k(float* __restrict__ pv, const int* __restrict__ pi_,
                           float* __restrict__ tv, int* __restrict__ ti_) {
    int row = blockIdx.x * blockDim.x + threadIdx.x;
    if (row >= N_ROWS) return;
    for (int sel = 0; sel < KNB; ++sel) {
        float best = -1e30f; long bslot = -1;
        for (int js = 0; js < JSPLIT; ++js) {
            size_t base = ((size_t)js * N_ROWS + row) * KNB;
            for (int k = 0; k < KNB; ++k) {
                float v = pv[base + k];
                if (v > best) { best = v; bslot = (long)(base + k); }
            }
        }
        tv[(size_t)row * KNB + sel] = best;
        ti_[(size_t)row * KNB + sel] = pi_[bslot];
        pv[bslot] = -1e30f;
    }
}

// ---------------- graph build ----------------
__global__ void edgecount_k(const float* __restrict__ tv, const int* __restrict__ ti_,
                            float* __restrict__ deg, int* __restrict__ cnt) {
    int e = blockIdx.x * blockDim.x + threadIdx.x;
    if (e >= N_ROWS * KNB) return;
    int i = e / KNB;
    int j = ti_[e];
    float v = fmaxf(tv[e], 0.f);
    float wv = 0.5f * v * v * v;
    atomicAdd(&deg[i], wv);
    atomicAdd(&deg[j], wv);
    atomicAdd(&cnt[i], 1);
    atomicAdd(&cnt[j], 1);
}

__global__ __launch_bounds__(1024) void scan_k(const int* __restrict__ cnt,
                                               int* __restrict__ rowptr,
                                               int* __restrict__ cur,
                                               const float* __restrict__ deg,
                                               float* __restrict__ dis) {
    __shared__ int sb[1024];
    int t = threadIdx.x;
    int carry = 0;
    for (int base = 0; base < N_ROWS; base += 1024) {
        int idx = base + t;
        int x = (idx < N_ROWS) ? cnt[idx] : 0;
        sb[t] = x;
        __syncthreads();
        for (int offc = 1; offc < 1024; offc <<= 1) {
            int add = (t >= offc) ? sb[t - offc] : 0;
            __syncthreads();
            sb[t] += add;
            __syncthreads();
        }
        int incl = sb[t];
        int tot = sb[1023];
        if (idx < N_ROWS) {
            rowptr[idx + 1] = carry + incl;
            cur[idx] = carry + incl - x;
            if (idx == 0) rowptr[0] = 0;
            dis[idx] = 1.0f / (sqrtf(deg[idx] + EPSV));
        }
        __syncthreads();
        carry += tot;
    }
}

__global__ void fill_k(const float* __restrict__ tv, const int* __restrict__ ti_,
                       const float* __restrict__ dis, int* __restrict__ cur,
                       int* __restrict__ cols, float* __restrict__ wts) {
    int e = blockIdx.x * blockDim.x + threadIdx.x;
    if (e >= N_ROWS * KNB) return;
    int i = e / KNB;
    int j = ti_[e];
    float v = fmaxf(tv[e], 0.f);
    float wv = 0.5f * v * v * v;
    float s = 0.99f * wv * dis[i] * dis[j];   // ALPHA folded into edge weight
    int p1 = atomicAdd(&cur[i], 1); cols[p1] = j; wts[p1] = s;
    int p2 = atomicAdd(&cur[j], 1); cols[p2] = i; wts[p2] = s;
}

// ---------------- sparse propagation step (float4, 16B/lane) ----------------
__global__ __launch_bounds__(256) void spmv_k(const int* __restrict__ rowptr,
                                              const int* __restrict__ cols,
                                              const float* __restrict__ wts,
                                              const float* __restrict__ Zin,
                                              const float* __restrict__ Y,
                                              float* __restrict__ Zout) {
    int i = blockIdx.x;
    int b = rowptr[i], e = rowptr[i + 1];
    int nnz = e - b;
    __shared__ int   cs[MAXE];
    __shared__ float wsh[MAXE];
    int nl = min(nnz, MAXE);
    for (int t = threadIdx.x; t < nl; t += 256) { cs[t] = cols[b + t]; wsh[t] = wts[b + t]; }
    __syncthreads();
    int t = threadIdx.x;
    if (t < NCLS / 4) {
        const float beta = (float)(1.0 - 0.99);
        float4 y = ((const float4*)(Y + (size_t)i * NCLS))[t];
        float4 acc = make_float4(beta * y.x, beta * y.y, beta * y.z, beta * y.w);
        for (int k = 0; k < nl; ++k) {
            float wv = wsh[k];
            float4 z = ((const float4*)(Zin + (size_t)cs[k] * NCLS))[t];
            acc.x += wv * z.x; acc.y += wv * z.y; acc.z += wv * z.z; acc.w += wv * z.w;
        }
        for (int k = MAXE; k < nnz; ++k) {
            float wv = wts[b + k];
            float4 z = ((const float4*)(Zin + (size_t)cols[b + k] * NCLS))[t];
            acc.x += wv * z.x; acc.y += wv * z.y; acc.z += wv * z.z; acc.w += wv * z.w;
        }
        ((float4*)(Zout + (size_t)i * NCLS))[t] = acc;
    }
}

extern "C" void kernel_launch(void* const* d_in, const int* in_sizes, int n_in,
                              void* d_out, int out_size, void* d_ws, size_t ws_size,
                              hipStream_t stream) {
    const float* feat = (const float*)d_in[0];
    const float* cw   = (const float*)d_in[1];
    float* out = (float*)d_out;
    char* ws = (char*)d_ws;
    size_t off = 0;
    auto alloc = [&](size_t b) { size_t o = off; off = (off + b + 255) & ~(size_t)255; return o; };
    unsigned short* nfh = (unsigned short*)(ws + alloc((size_t)N_ROWS * DIM * 2));
    unsigned short* nfl = (unsigned short*)(ws + alloc((size_t)N_ROWS * DIM * 2));
    unsigned short* cwh = (unsigned short*)(ws + alloc((size_t)NCLS * DIM * 2));
    unsigned short* cwl = (unsigned short*)(ws + alloc((size_t)NCLS * DIM * 2));
    float* rnorm = (float*)(ws + alloc(N_ROWS * 4));
    float* ZA   = (float*)(ws + alloc((size_t)N_ROWS * NCLS * 4));   // logits, then Z ping buffer
    float* Y    = (float*)(ws + alloc((size_t)N_ROWS * NCLS * 4));
    float* pv   = (float*)(ws + alloc((size_t)JSPLIT * N_ROWS * KNB * 4));
    int*   pi_  = (int*)  (ws + alloc((size_t)JSPLIT * N_ROWS * KNB * 4));
    float* tv   = (float*)(ws + alloc((size_t)N_ROWS * KNB * 4));
    int*   ti_  = (int*)  (ws + alloc((size_t)N_ROWS * KNB * 4));
    float* deg  = (float*)(ws + alloc(N_ROWS * 4));
    int*   cnt  = (int*)  (ws + alloc(N_ROWS * 4));
    int*   rowptr = (int*)(ws + alloc((N_ROWS + 1) * 4));
    int*   cur  = (int*)  (ws + alloc(N_ROWS * 4));
    float* dis  = (float*)(ws + alloc(N_ROWS * 4));
    int*   cols = (int*)  (ws + alloc((size_t)2 * N_ROWS * KNB * 4));
    float* wts  = (float*)(ws + alloc((size_t)2 * N_ROWS * KNB * 4));
    if (off > ws_size) return;

    hipMemsetAsync(deg, 0, N_ROWS * 4, stream);
    hipMemsetAsync(cnt, 0, N_ROWS * 4, stream);

    rownorm2_k<<<N_ROWS, 192, 0, stream>>>(feat, nfh, nfl, rnorm);
    split_k<<<(NCLS * DIM / 4 + 255) / 256, 256, 0, stream>>>(cw, cwh, cwl, NCLS * DIM / 4);

    dim3 gl(NRT, NCT);
    gemm2_k<<<gl, 256, 0, stream>>>(nfh, nfl, cwh, cwl, rnorm, ZA);
    softmax_k<<<N_ROWS, 256, 0, stream>>>(ZA, Y);

    simtopk_k<<<NRT * JSPLIT, 256, 0, stream>>>(nfh, nfl, pv, pi_);
    topmerge_k<<<(N_ROWS + 255) / 256, 256, 0, stream>>>(pv, pi_, tv, ti_);

    edgecount_k<<<(N_ROWS * KNB + 255) / 256, 256, 0, stream>>>(tv, ti_, deg, cnt);
    scan_k<<<1, 1024, 0, stream>>>(cnt, rowptr, cur, deg, dis);
    fill_k<<<(N_ROWS * KNB + 255) / 256, 256, 0, stream>>>(tv, ti_, dis, cur, cols, wts);

    const float* zin = Y;
    for (int it = 0; it < NITER; ++it) {
        float* zout = (it & 1) ? out : ZA;     // it=19 (odd) lands on d_out
        spmv_k<<<N_ROWS, 256, 0, stream>>>(rowptr, cols, wts, zin, Y, zout);
        zin = zout;
    }
}